// Round 1
// baseline (3947.483 us; speedup 1.0000x reference)
//
#include <hip/hip_runtime.h>
#include <cmath>

#define TBUF 1024
#define RCH  256

// ---------------- weight transforms ----------------
// wT[i][kappa][o']  kappa = c (cur tap, w[...,1]) or 256+c (prev tap, w[...,0])
// o' < 256 -> filter, o' >= 256 -> gate
__global__ __launch_bounds__(256) void transform_fg(
    const float* __restrict__ wf, const float* __restrict__ wg, float* __restrict__ wT)
{
  int idx = blockIdx.x * 256 + threadIdx.x;   // < 32*512*512
  int op  = idx & 511;
  int kap = (idx >> 9) & 511;
  int i   = idx >> 18;
  int o = op & 255, c = kap & 255;
  int k = (kap < 256) ? 1 : 0;
  const float* src = (op < 256) ? wf : wg;
  wT[idx] = src[(((i * 256 + o) * 256 + c) << 1) + k];
}

// wrT[i][c][o] = w_res[i][o][c]
__global__ __launch_bounds__(256) void transform_res(
    const float* __restrict__ wr, float* __restrict__ wrT)
{
  int idx = blockIdx.x * 256 + threadIdx.x;   // < 32*256*256
  int o = idx & 255;
  int c = (idx >> 8) & 255;
  int i = idx >> 16;
  wrT[idx] = wr[(i * 256 + o) * 256 + c];
}

// wskT[i][c][s] = w_skip[i][s][c]
__global__ __launch_bounds__(256) void transform_skip(
    const float* __restrict__ wsk, float* __restrict__ wskT)
{
  int idx = blockIdx.x * 256 + threadIdx.x;   // < 32*256*128
  int s = idx & 127;
  int c = (idx >> 7) & 255;
  int i = idx >> 15;
  wskT[idx] = wsk[(i * 128 + s) * 256 + c];
}

// ---------------- input conv (F=32 -> R=256, K=2, d=1) ----------------
// xb[b][tt][r], tt = t - 1024, valid outputs tt in [3,1023]
__global__ __launch_bounds__(256) void in_conv(
    const float* __restrict__ X, const float* __restrict__ w_in,
    const float* __restrict__ b_in, float* __restrict__ xb)
{
  int g = blockIdx.x;       // 0..127 (8 time steps each)
  int b = blockIdx.y;
  int r = threadIdx.x;      // 0..255
  __shared__ float Xs[9][32];
  int tt0 = 3 + g * 8;
  int t0  = tt0 + 1024;
  for (int idx = r; idx < 288; idx += 256) {
    int row = idx >> 5, f = idx & 31;
    int t = t0 - 1 + row;
    if (t > 2047) t = 2047;
    Xs[row][f] = X[(b * 2048 + t) * 32 + f];
  }
  __syncthreads();
  float acc[8] = {0,0,0,0,0,0,0,0};
  const float* w = w_in + r * 64;   // [f][2]
  #pragma unroll
  for (int f = 0; f < 32; f++) {
    float w0 = w[f * 2 + 0];
    float w1 = w[f * 2 + 1];
    #pragma unroll
    for (int j = 0; j < 8; j++)
      acc[j] = fmaf(w1, Xs[j + 1][f], fmaf(w0, Xs[j][f], acc[j]));
  }
  float bias = b_in[r];
  #pragma unroll
  for (int j = 0; j < 8; j++) {
    int tt = tt0 + j;
    if (tt <= 1023)
      xb[((size_t)b * TBUF + tt) * RCH + r] = acc[j] + bias;
  }
}

// ---------------- gated dilated conv: pre_f/pre_g GEMM + tanh*sigmoid ----------------
// grid: (tiles, 4, 16). Tile j covers tt in [1024-(j+1)*64, 1024-j*64).
__global__ __launch_bounds__(256) void conv_layer(
    const float* __restrict__ xb, float* __restrict__ zb,
    const float* __restrict__ wT, const float* __restrict__ bf,
    const float* __restrict__ bg, int d, int t_lo)
{
  __shared__ float As[16][68];   // [k in chunk][row], padded for b128 align
  __shared__ float Bf[16][64];
  __shared__ float Bg[16][64];
  const int tid   = threadIdx.x;
  const int ttb   = TBUF - ((int)blockIdx.x + 1) * 64;
  const int obase = blockIdx.y * 64;
  const int b     = blockIdx.z;
  const int tx    = tid & 15;
  const int ty    = tid >> 4;
  const int lrow  = tid >> 2;
  const int lc4   = (tid & 3) << 2;
  const float* xB = xb + (size_t)b * (TBUF * RCH);
  float accf[4][4] = {};
  float accg[4][4] = {};
  for (int k0 = 0; k0 < 512; k0 += 16) {
    int tap = k0 >> 8;                     // 0: cur tap, 1: prev tap
    int tt  = ttb + lrow - tap * d;
    if (tt < 0) tt = 0;                    // garbage rows only, discarded
    int cb = (k0 & 255) + lc4;
    float4 av = *(const float4*)(xB + (size_t)tt * RCH + cb);
    As[lc4 + 0][lrow] = av.x;
    As[lc4 + 1][lrow] = av.y;
    As[lc4 + 2][lrow] = av.z;
    As[lc4 + 3][lrow] = av.w;
    const float* wrow = wT + (size_t)(k0 + ty) * 512 + obase + tx * 4;
    *(float4*)&Bf[ty][tx * 4] = *(const float4*)(wrow);
    *(float4*)&Bg[ty][tx * 4] = *(const float4*)(wrow + 256);
    __syncthreads();
    #pragma unroll
    for (int kk = 0; kk < 16; kk++) {
      float4 a4 = *(const float4*)&As[kk][ty * 4];
      float4 f4 = *(const float4*)&Bf[kk][tx * 4];
      float4 g4 = *(const float4*)&Bg[kk][tx * 4];
      float a[4] = {a4.x, a4.y, a4.z, a4.w};
      float f[4] = {f4.x, f4.y, f4.z, f4.w};
      float g[4] = {g4.x, g4.y, g4.z, g4.w};
      #pragma unroll
      for (int mi = 0; mi < 4; mi++)
        #pragma unroll
        for (int ni = 0; ni < 4; ni++) {
          accf[mi][ni] = fmaf(a[mi], f[ni], accf[mi][ni]);
          accg[mi][ni] = fmaf(a[mi], g[ni], accg[mi][ni]);
        }
    }
    __syncthreads();
  }
  #pragma unroll
  for (int mi = 0; mi < 4; mi++) {
    int tt = ttb + ty * 4 + mi;
    if (tt < t_lo) continue;
    float* zp = zb + ((size_t)b * TBUF + tt) * RCH + obase + tx * 4;
    float r[4];
    #pragma unroll
    for (int ni = 0; ni < 4; ni++) {
      int o = obase + tx * 4 + ni;
      float pf = accf[mi][ni] + bf[o];
      float pg = accg[mi][ni] + bg[o];
      r[ni] = tanhf(pf) * (1.0f / (1.0f + expf(-pg)));
    }
    float4 zv = {r[0], r[1], r[2], r[3]};
    *(float4*)zp = zv;
  }
}

// ---------------- res 1x1: fx = z @ wrT + b_res; x += fx; snapshot fx at tt=1023 ----------------
__global__ __launch_bounds__(256) void res_layer(
    const float* __restrict__ zb, float* __restrict__ xb,
    const float* __restrict__ wrT, const float* __restrict__ br,
    int t_lo, float* __restrict__ fxsnap)
{
  __shared__ float As[16][68];
  __shared__ float Bs[16][64];
  const int tid   = threadIdx.x;
  const int ttb   = TBUF - ((int)blockIdx.x + 1) * 64;
  const int obase = blockIdx.y * 64;
  const int b     = blockIdx.z;
  const int tx    = tid & 15;
  const int ty    = tid >> 4;
  const int lrow  = tid >> 2;
  const int lc4   = (tid & 3) << 2;
  const float* zB = zb + (size_t)b * (TBUF * RCH);
  float acc[4][4] = {};
  for (int k0 = 0; k0 < 256; k0 += 16) {
    int tt = ttb + lrow;
    int cb = k0 + lc4;
    float4 av = *(const float4*)(zB + (size_t)tt * RCH + cb);
    As[lc4 + 0][lrow] = av.x;
    As[lc4 + 1][lrow] = av.y;
    As[lc4 + 2][lrow] = av.z;
    As[lc4 + 3][lrow] = av.w;
    const float* wrow = wrT + (size_t)(k0 + ty) * 256 + obase + tx * 4;
    *(float4*)&Bs[ty][tx * 4] = *(const float4*)(wrow);
    __syncthreads();
    #pragma unroll
    for (int kk = 0; kk < 16; kk++) {
      float4 a4 = *(const float4*)&As[kk][ty * 4];
      float4 w4 = *(const float4*)&Bs[kk][tx * 4];
      float a[4] = {a4.x, a4.y, a4.z, a4.w};
      float w[4] = {w4.x, w4.y, w4.z, w4.w};
      #pragma unroll
      for (int mi = 0; mi < 4; mi++)
        #pragma unroll
        for (int ni = 0; ni < 4; ni++)
          acc[mi][ni] = fmaf(a[mi], w[ni], acc[mi][ni]);
    }
    __syncthreads();
  }
  #pragma unroll
  for (int mi = 0; mi < 4; mi++) {
    int tt = ttb + ty * 4 + mi;
    if (tt < t_lo) continue;
    size_t off = ((size_t)b * TBUF + tt) * RCH + obase + tx * 4;
    float4 xo = *(const float4*)(xb + off);
    float fx[4];
    #pragma unroll
    for (int ni = 0; ni < 4; ni++)
      fx[ni] = acc[mi][ni] + br[obase + tx * 4 + ni];
    float4 xn = {fx[0] + xo.x, fx[1] + xo.y, fx[2] + xo.z, fx[3] + xo.w};
    *(float4*)(xb + off) = xn;
    if (tt == 1023) {
      float4 fv = {fx[0], fx[1], fx[2], fx[3]};
      *(float4*)(fxsnap + (size_t)b * RCH + obase + tx * 4) = fv;
    }
  }
}

// ---------------- skip + head (only t = T-1 matters) ----------------
__global__ __launch_bounds__(256) void head_kernel(
    const float* __restrict__ fxsnap, const float* __restrict__ wskT,
    const float* __restrict__ b_skip, const float* __restrict__ w_o1,
    const float* __restrict__ b_o1, const float* __restrict__ w_o2,
    const float* __restrict__ b_o2, const float* __restrict__ w_lin,
    const float* __restrict__ b_lin, const float* __restrict__ Xex,
    float* __restrict__ out)
{
  int b = blockIdx.x;
  int tid = threadIdx.x;
  __shared__ float fxsh[256];
  __shared__ float sk[128];
  __shared__ float h1[64];
  __shared__ float hc[80];
  float acc = 0.f;
  for (int i = 0; i < 32; i++) {
    __syncthreads();
    fxsh[tid] = fxsnap[((size_t)i * 16 + b) * 256 + tid];
    __syncthreads();
    if (tid < 128) {
      float a = b_skip[i * 128 + tid];
      const float* wp = wskT + (size_t)i * 256 * 128 + tid;
      #pragma unroll 4
      for (int c = 0; c < 256; c++)
        a = fmaf(wp[c * 128], fxsh[c], a);
      acc += a;
    }
  }
  __syncthreads();
  if (tid < 128) sk[tid] = fmaxf(acc, 0.f);
  __syncthreads();
  if (tid < 64) {
    float a = b_o1[tid];
    for (int s = 0; s < 128; s++) a = fmaf(w_o1[tid * 128 + s], sk[s], a);
    h1[tid] = fmaxf(a, 0.f);
  }
  __syncthreads();
  if (tid < 64) {
    float a = b_o2[tid];
    for (int j = 0; j < 64; j++) a = fmaf(w_o2[tid * 64 + j], h1[j], a);
    hc[tid] = fmaxf(a, 0.f);             // relu applied after concat
  }
  if (tid >= 64 && tid < 80) hc[tid] = fmaxf(Xex[b * 16 + (tid - 64)], 0.f);
  __syncthreads();
  if (tid < 24) {
    float a = b_lin[tid];
    for (int j = 0; j < 80; j++) a = fmaf(w_lin[tid * 80 + j], hc[j], a);
    out[b * 24 + tid] = a;
  }
}

extern "C" void kernel_launch(void* const* d_in, const int* in_sizes, int n_in,
                              void* d_out, int out_size, void* d_ws, size_t ws_size,
                              hipStream_t stream)
{
  (void)in_sizes; (void)n_in; (void)out_size; (void)ws_size;
  const float* X     = (const float*)d_in[0];
  const float* Xex   = (const float*)d_in[1];
  const float* w_in  = (const float*)d_in[2];
  const float* b_in  = (const float*)d_in[3];
  const float* w_f   = (const float*)d_in[4];
  const float* b_f   = (const float*)d_in[5];
  const float* w_g   = (const float*)d_in[6];
  const float* b_g   = (const float*)d_in[7];
  const float* w_r   = (const float*)d_in[8];
  const float* b_r   = (const float*)d_in[9];
  const float* w_s   = (const float*)d_in[10];
  const float* b_s   = (const float*)d_in[11];
  const float* w_o1  = (const float*)d_in[12];
  const float* b_o1  = (const float*)d_in[13];
  const float* w_o2  = (const float*)d_in[14];
  const float* b_o2  = (const float*)d_in[15];
  const float* w_lin = (const float*)d_in[16];
  const float* b_lin = (const float*)d_in[17];

  float* ws   = (float*)d_ws;
  float* wT   = ws;                       // 32*512*512 = 8388608
  float* wrT  = wT  + 8388608;            // 32*256*256 = 2097152
  float* wskT = wrT + 2097152;            // 32*256*128 = 1048576
  float* xb   = wskT + 1048576;           // 16*1024*256 = 4194304
  float* zb   = xb  + 4194304;            // 16*1024*256 = 4194304
  float* fxs  = zb  + 4194304;            // 32*16*256  = 131072

  transform_fg  <<<32768, 256, 0, stream>>>(w_f, w_g, wT);
  transform_res <<<8192,  256, 0, stream>>>(w_r, wrT);
  transform_skip<<<4096,  256, 0, stream>>>(w_s, wskT);
  in_conv<<<dim3(128, 16), 256, 0, stream>>>(X, w_in, b_in, xb);

  // suffix-window sizes: w[i] = w[i+1] + 2^(i%8), w[32] = 1
  static const int wI[33] = {1021,1020,1018,1014,1006,990,958,894,
                             766,765,763,759,751,735,703,639,
                             511,510,508,504,496,480,448,384,
                             256,255,253,249,241,225,193,129,1};
  for (int i = 0; i < 32; i++) {
    int d     = 1 << (i & 7);
    int Wout  = wI[i + 1];
    int t_lo  = TBUF - Wout;
    int tiles = (Wout + 63) / 64;
    conv_layer<<<dim3(tiles, 4, 16), 256, 0, stream>>>(
        xb, zb, wT + (size_t)i * 512 * 512, b_f + i * 256, b_g + i * 256, d, t_lo);
    res_layer<<<dim3(tiles, 4, 16), 256, 0, stream>>>(
        zb, xb, wrT + (size_t)i * 256 * 256, b_r + i * 256, t_lo, fxs + (size_t)i * 16 * 256);
  }
  head_kernel<<<16, 256, 0, stream>>>(fxs, wskT, b_s, w_o1, b_o1, w_o2, b_o2,
                                      w_lin, b_lin, Xex, (float*)d_out);
}

// Round 2
// 2738.434 us; speedup vs baseline: 1.4415x; 1.4415x over previous
//
#include <hip/hip_runtime.h>
#include <cmath>

#define TBUF 1024
#define RCH  256

typedef __bf16 bf16x8 __attribute__((ext_vector_type(8)));
typedef float  f32x4  __attribute__((ext_vector_type(4)));

__device__ inline unsigned short f2bf(float f) {
  unsigned u = __builtin_bit_cast(unsigned, f);
  u += 0x7FFFu + ((u >> 16) & 1u);
  return (unsigned short)(u >> 16);
}

// ---------------- weight transforms ----------------
// Wb[i][o'][kappa] bf16 (B^T row-major).  o'<256 -> filter o, o'>=256 -> gate o-256.
// kappa<256 -> current tap (w[...,1]), kappa>=256 -> previous tap (w[...,0]).
__global__ __launch_bounds__(256) void transform_fgb(
    const float* __restrict__ wf, const float* __restrict__ wg, unsigned short* __restrict__ Wb)
{
  int idx = blockIdx.x * 256 + threadIdx.x;    // < 32*512*512
  int kap = idx & 511;
  int op  = (idx >> 9) & 511;
  int i   = idx >> 18;
  int o = op & 255, c = kap & 255;
  int k = (kap < 256) ? 1 : 0;
  const float* src = (op < 256) ? wf : wg;
  Wb[idx] = f2bf(src[(((i * 256 + o) * 256 + c) << 1) + k]);
}

// Wrb[i][o][c] bf16 (w_res already [o][c])
__global__ __launch_bounds__(256) void transform_resb(
    const float* __restrict__ wr, unsigned short* __restrict__ Wrb)
{
  int idx = blockIdx.x * 256 + threadIdx.x;    // < 32*256*256/4
  float4 v = ((const float4*)wr)[idx];
  uint2 o;
  o.x = (unsigned)f2bf(v.x) | ((unsigned)f2bf(v.y) << 16);
  o.y = (unsigned)f2bf(v.z) | ((unsigned)f2bf(v.w) << 16);
  ((uint2*)Wrb)[idx] = o;
}

// wskT[i][c][s] = w_skip[i][s][c]  (fp32, for head)
__global__ __launch_bounds__(256) void transform_skip(
    const float* __restrict__ wsk, float* __restrict__ wskT)
{
  int idx = blockIdx.x * 256 + threadIdx.x;    // < 32*256*128
  int s = idx & 127;
  int c = (idx >> 7) & 255;
  int i = idx >> 15;
  wskT[idx] = wsk[(i * 128 + s) * 256 + c];
}

// ---------------- input conv (F=32 -> R=256, K=2, d=1) ----------------
__global__ __launch_bounds__(256) void in_conv(
    const float* __restrict__ X, const float* __restrict__ w_in,
    const float* __restrict__ b_in, float* __restrict__ xb,
    unsigned short* __restrict__ xbb)
{
  int g = blockIdx.x;       // 0..127 (8 time steps each)
  int b = blockIdx.y;
  int r = threadIdx.x;      // 0..255
  __shared__ float Xs[9][32];
  int tt0 = 3 + g * 8;
  int t0  = tt0 + 1024;
  for (int idx = r; idx < 288; idx += 256) {
    int row = idx >> 5, f = idx & 31;
    int t = t0 - 1 + row;
    if (t > 2047) t = 2047;
    Xs[row][f] = X[(b * 2048 + t) * 32 + f];
  }
  if (g == 0) {
    #pragma unroll
    for (int t2 = 0; t2 < 3; t2++) {
      size_t off = ((size_t)b * TBUF + t2) * RCH + r;
      xb[off] = 0.f; xbb[off] = 0;
    }
  }
  __syncthreads();
  float acc[8] = {0,0,0,0,0,0,0,0};
  const float* w = w_in + r * 64;
  #pragma unroll
  for (int f = 0; f < 32; f++) {
    float w0 = w[f * 2 + 0];
    float w1 = w[f * 2 + 1];
    #pragma unroll
    for (int j = 0; j < 8; j++)
      acc[j] = fmaf(w1, Xs[j + 1][f], fmaf(w0, Xs[j][f], acc[j]));
  }
  float bias = b_in[r];
  #pragma unroll
  for (int j = 0; j < 8; j++) {
    int tt = tt0 + j;
    if (tt <= 1023) {
      float v = acc[j] + bias;
      size_t off = ((size_t)b * TBUF + tt) * RCH + r;
      xb[off] = v; xbb[off] = f2bf(v);
    }
  }
}

// ---------------- gated dilated conv, MFMA ----------------
// Block: 256 thr = 4 waves (2wm x 2wn). Tile M=128 (tt), O=128 (both f and g).
// grid (ceil(Wout/128), 2, 16)
__global__ __launch_bounds__(256) void conv_mfma(
    const unsigned short* __restrict__ xbb, unsigned short* __restrict__ zbb,
    const unsigned short* __restrict__ Wb, const float* __restrict__ bF,
    const float* __restrict__ bG, int dd, int t_lo)
{
  __shared__ __align__(16) unsigned short As[128 * 32];
  __shared__ __align__(16) unsigned short Bs[256 * 32];
  const int tid  = threadIdx.x;
  const int lane = tid & 63;
  const int w    = tid >> 6;
  const int wm   = w >> 1, wn = w & 1;
  const int tt0  = t_lo + (int)blockIdx.x * 128;
  const int ob   = (int)blockIdx.y * 128;
  const int b    = blockIdx.z;
  const unsigned short* xB = xbb + ((size_t)b << 18);   // b*1024*256

  f32x4 accf[4][4] = {};
  f32x4 accg[4][4] = {};

  const int l15 = lane & 15;
  const int lk  = (lane >> 4) << 3;   // 0,8,16,24

  for (int k0 = 0; k0 < 512; k0 += 32) {
    const int tap = k0 >> 8;
    const int cb  = k0 & 255;
    uint4 ra[2], rb[4];
    #pragma unroll
    for (int it = 0; it < 2; it++) {
      int cidx = it * 256 + tid;
      int r = cidx >> 2, co = (cidx & 3) << 3;
      int tt = tt0 + r - tap * dd;
      tt = min(max(tt, 0), 1023);
      ra[it] = *(const uint4*)&xB[((size_t)tt << 8) + cb + co];
    }
    #pragma unroll
    for (int it = 0; it < 4; it++) {
      int cidx = it * 256 + tid;
      int r = cidx >> 2, co = (cidx & 3) << 3;
      int orow = (r < 128) ? (ob + r) : (128 + ob + r);  // g rows: 256+ob+(r-128)
      rb[it] = *(const uint4*)&Wb[(size_t)orow * 512 + k0 + co];
    }
    __syncthreads();
    #pragma unroll
    for (int it = 0; it < 2; it++) {
      int cidx = it * 256 + tid;
      *(uint4*)&As[(cidx >> 2) * 32 + ((cidx & 3) << 3)] = ra[it];
    }
    #pragma unroll
    for (int it = 0; it < 4; it++) {
      int cidx = it * 256 + tid;
      *(uint4*)&Bs[(cidx >> 2) * 32 + ((cidx & 3) << 3)] = rb[it];
    }
    __syncthreads();
    bf16x8 af[4], bfr[4], bgr[4];
    #pragma unroll
    for (int mf = 0; mf < 4; mf++)
      af[mf] = *(const bf16x8*)&As[(wm * 64 + mf * 16 + l15) * 32 + lk];
    #pragma unroll
    for (int nf = 0; nf < 4; nf++) {
      int rr = wn * 64 + nf * 16 + l15;
      bfr[nf] = *(const bf16x8*)&Bs[rr * 32 + lk];
      bgr[nf] = *(const bf16x8*)&Bs[(128 + rr) * 32 + lk];
    }
    #pragma unroll
    for (int mf = 0; mf < 4; mf++)
      #pragma unroll
      for (int nf = 0; nf < 4; nf++) {
        accf[mf][nf] = __builtin_amdgcn_mfma_f32_16x16x32_bf16(af[mf], bfr[nf], accf[mf][nf], 0, 0, 0);
        accg[mf][nf] = __builtin_amdgcn_mfma_f32_16x16x32_bf16(af[mf], bgr[nf], accg[mf][nf], 0, 0, 0);
      }
    __syncthreads();
  }

  unsigned short* zB = zbb + ((size_t)b << 18);
  #pragma unroll
  for (int mf = 0; mf < 4; mf++) {
    int ttrow = tt0 + wm * 64 + mf * 16 + (lane >> 4) * 4;
    #pragma unroll
    for (int nf = 0; nf < 4; nf++) {
      int o = ob + wn * 64 + nf * 16 + l15;
      float bfv = bF[o], bgv = bG[o];
      #pragma unroll
      for (int j = 0; j < 4; j++) {
        int tt = ttrow + j;
        if (tt > 1023) continue;
        float pf = accf[mf][nf][j] + bfv;
        float pg = accg[mf][nf][j] + bgv;
        float z = tanhf(pf) * (1.0f / (1.0f + __expf(-pg)));
        zB[((size_t)tt << 8) + o] = f2bf(z);
      }
    }
  }
}

// ---------------- res 1x1 MFMA: fx = z @ Wrb^T + b_r; x += fx (fp32 + bf16 mirror) ----------------
// grid (ceil(Wout/128), 2, 16)
__global__ __launch_bounds__(256) void res_mfma(
    const unsigned short* __restrict__ zbb, float* __restrict__ xb,
    unsigned short* __restrict__ xbb, const unsigned short* __restrict__ Wrb,
    const float* __restrict__ bR, int t_lo, float* __restrict__ fxs_i)
{
  __shared__ __align__(16) unsigned short As[128 * 32];
  __shared__ __align__(16) unsigned short Bs[128 * 32];
  const int tid  = threadIdx.x;
  const int lane = tid & 63;
  const int w    = tid >> 6;
  const int wm   = w >> 1, wn = w & 1;
  const int tt0  = t_lo + (int)blockIdx.x * 128;
  const int ob   = (int)blockIdx.y * 128;
  const int b    = blockIdx.z;
  const unsigned short* zB = zbb + ((size_t)b << 18);

  f32x4 acc[4][4] = {};
  const int l15 = lane & 15;
  const int lk  = (lane >> 4) << 3;

  for (int k0 = 0; k0 < 256; k0 += 32) {
    uint4 ra[2], rb[2];
    #pragma unroll
    for (int it = 0; it < 2; it++) {
      int cidx = it * 256 + tid;
      int r = cidx >> 2, co = (cidx & 3) << 3;
      int tt = min(tt0 + r, 1023);
      ra[it] = *(const uint4*)&zB[((size_t)tt << 8) + k0 + co];
    }
    #pragma unroll
    for (int it = 0; it < 2; it++) {
      int cidx = it * 256 + tid;
      int r = cidx >> 2, co = (cidx & 3) << 3;
      rb[it] = *(const uint4*)&Wrb[(size_t)(ob + r) * 256 + k0 + co];
    }
    __syncthreads();
    #pragma unroll
    for (int it = 0; it < 2; it++) {
      int cidx = it * 256 + tid;
      *(uint4*)&As[(cidx >> 2) * 32 + ((cidx & 3) << 3)] = ra[it];
    }
    #pragma unroll
    for (int it = 0; it < 2; it++) {
      int cidx = it * 256 + tid;
      *(uint4*)&Bs[(cidx >> 2) * 32 + ((cidx & 3) << 3)] = rb[it];
    }
    __syncthreads();
    bf16x8 af[4], bw[4];
    #pragma unroll
    for (int mf = 0; mf < 4; mf++)
      af[mf] = *(const bf16x8*)&As[(wm * 64 + mf * 16 + l15) * 32 + lk];
    #pragma unroll
    for (int nf = 0; nf < 4; nf++)
      bw[nf] = *(const bf16x8*)&Bs[(wn * 64 + nf * 16 + l15) * 32 + lk];
    #pragma unroll
    for (int mf = 0; mf < 4; mf++)
      #pragma unroll
      for (int nf = 0; nf < 4; nf++)
        acc[mf][nf] = __builtin_amdgcn_mfma_f32_16x16x32_bf16(af[mf], bw[nf], acc[mf][nf], 0, 0, 0);
    __syncthreads();
  }

  float* xB = xb + ((size_t)b << 18);
  unsigned short* xbbB = xbb + ((size_t)b << 18);
  #pragma unroll
  for (int mf = 0; mf < 4; mf++) {
    int ttrow = tt0 + wm * 64 + mf * 16 + (lane >> 4) * 4;
    #pragma unroll
    for (int nf = 0; nf < 4; nf++) {
      int o = ob + wn * 64 + nf * 16 + l15;
      float brv = bR[o];
      #pragma unroll
      for (int j = 0; j < 4; j++) {
        int tt = ttrow + j;
        if (tt > 1023) continue;
        size_t off = ((size_t)tt << 8) + o;
        float fx = acc[mf][nf][j] + brv;
        float xn = xB[off] + fx;
        xB[off] = xn;
        xbbB[off] = f2bf(xn);
        if (tt == 1023) fxs_i[(size_t)b * 256 + o] = fx;
      }
    }
  }
}

// ---------------- head ----------------
// skip partials: grid (32 layers, 16 batch), 128 threads
__global__ __launch_bounds__(128) void skip_partial(
    const float* __restrict__ fxs, const float* __restrict__ wskT,
    const float* __restrict__ b_skip, float* __restrict__ part)
{
  int i = blockIdx.x, b = blockIdx.y, s = threadIdx.x;
  __shared__ float fxsh[256];
  fxsh[s]       = fxs[((size_t)i * 16 + b) * 256 + s];
  fxsh[s + 128] = fxs[((size_t)i * 16 + b) * 256 + s + 128];
  __syncthreads();
  float a = b_skip[i * 128 + s];
  const float* wp = wskT + (size_t)i * 256 * 128 + s;
  #pragma unroll 4
  for (int c = 0; c < 256; c++)
    a = fmaf(wp[c * 128], fxsh[c], a);
  part[((size_t)i * 16 + b) * 128 + s] = a;
}

__global__ __launch_bounds__(128) void head2(
    const float* __restrict__ part, const float* __restrict__ w_o1,
    const float* __restrict__ b_o1, const float* __restrict__ w_o2,
    const float* __restrict__ b_o2, const float* __restrict__ w_lin,
    const float* __restrict__ b_lin, const float* __restrict__ Xex,
    float* __restrict__ out)
{
  int b = blockIdx.x, tid = threadIdx.x;
  __shared__ float sk[128];
  __shared__ float h1[64];
  __shared__ float hc[80];
  float a = 0.f;
  for (int i = 0; i < 32; i++) a += part[((size_t)i * 16 + b) * 128 + tid];
  sk[tid] = fmaxf(a, 0.f);
  __syncthreads();
  if (tid < 64) {
    float a1 = b_o1[tid];
    for (int s = 0; s < 128; s++) a1 = fmaf(w_o1[tid * 128 + s], sk[s], a1);
    h1[tid] = fmaxf(a1, 0.f);
  }
  __syncthreads();
  if (tid < 64) {
    float a2 = b_o2[tid];
    for (int j = 0; j < 64; j++) a2 = fmaf(w_o2[tid * 64 + j], h1[j], a2);
    hc[tid] = fmaxf(a2, 0.f);
  }
  if (tid >= 64 && tid < 80) hc[tid] = fmaxf(Xex[b * 16 + (tid - 64)], 0.f);
  __syncthreads();
  if (tid < 24) {
    float a3 = b_lin[tid];
    for (int j = 0; j < 80; j++) a3 = fmaf(w_lin[tid * 80 + j], hc[j], a3);
    out[b * 24 + tid] = a3;
  }
}

extern "C" void kernel_launch(void* const* d_in, const int* in_sizes, int n_in,
                              void* d_out, int out_size, void* d_ws, size_t ws_size,
                              hipStream_t stream)
{
  (void)in_sizes; (void)n_in; (void)out_size; (void)ws_size;
  const float* X     = (const float*)d_in[0];
  const float* Xex   = (const float*)d_in[1];
  const float* w_in  = (const float*)d_in[2];
  const float* b_in  = (const float*)d_in[3];
  const float* w_f   = (const float*)d_in[4];
  const float* b_f   = (const float*)d_in[5];
  const float* w_g   = (const float*)d_in[6];
  const float* b_g   = (const float*)d_in[7];
  const float* w_r   = (const float*)d_in[8];
  const float* b_r   = (const float*)d_in[9];
  const float* w_s   = (const float*)d_in[10];
  const float* b_s   = (const float*)d_in[11];
  const float* w_o1  = (const float*)d_in[12];
  const float* b_o1  = (const float*)d_in[13];
  const float* w_o2  = (const float*)d_in[14];
  const float* b_o2  = (const float*)d_in[15];
  const float* w_lin = (const float*)d_in[16];
  const float* b_lin = (const float*)d_in[17];

  float* ws   = (float*)d_ws;
  float* wskT = ws;                        // 1,048,576 f
  float* xb   = wskT + 1048576;            // 4,194,304 f
  float* fxs  = xb   + 4194304;            // 131,072 f
  float* part = fxs  + 131072;             // 65,536 f
  unsigned short* Wb  = (unsigned short*)(part + 65536);   // 8,388,608 us
  unsigned short* Wrb = Wb  + 8388608;     // 2,097,152 us
  unsigned short* xbb = Wrb + 2097152;     // 4,194,304 us
  unsigned short* zbb = xbb + 4194304;     // 4,194,304 us

  transform_fgb <<<32768, 256, 0, stream>>>(w_f, w_g, Wb);
  transform_resb<<<2048,  256, 0, stream>>>(w_r, Wrb);
  transform_skip<<<4096,  256, 0, stream>>>(w_s, wskT);
  in_conv<<<dim3(128, 16), 256, 0, stream>>>(X, w_in, b_in, xb, xbb);

  // suffix-window sizes: w[i] = w[i+1] + 2^(i%8), w[32] = 1
  static const int wI[33] = {1021,1020,1018,1014,1006,990,958,894,
                             766,765,763,759,751,735,703,639,
                             511,510,508,504,496,480,448,384,
                             256,255,253,249,241,225,193,129,1};
  for (int i = 0; i < 32; i++) {
    int dd    = 1 << (i & 7);
    int Wout  = wI[i + 1];
    int t_lo  = TBUF - Wout;
    int tiles = (Wout + 127) / 128;
    conv_mfma<<<dim3(tiles, 2, 16), 256, 0, stream>>>(
        xbb, zbb, Wb + (size_t)i * 512 * 512, b_f + i * 256, b_g + i * 256, dd, t_lo);
    res_mfma<<<dim3(tiles, 2, 16), 256, 0, stream>>>(
        zbb, xb, xbb, Wrb + (size_t)i * 256 * 256, b_r + i * 256, t_lo,
        fxs + (size_t)i * 16 * 256);
  }
  skip_partial<<<dim3(32, 16), 128, 0, stream>>>(fxs, wskT, b_s, part);
  head2<<<16, 128, 0, stream>>>(part, w_o1, b_o1, w_o2, b_o2, w_lin, b_lin, Xex, (float*)d_out);
}

// Round 3
// 1195.867 us; speedup vs baseline: 3.3009x; 2.2899x over previous
//
#include <hip/hip_runtime.h>
#include <cmath>

#define TBUF 1024
#define RCH  256

typedef __bf16 bf16x8 __attribute__((ext_vector_type(8)));
typedef float  f32x4  __attribute__((ext_vector_type(4)));

__device__ inline unsigned short f2bf(float f) {
  unsigned u = __builtin_bit_cast(unsigned, f);
  u += 0x7FFFu + ((u >> 16) & 1u);
  return (unsigned short)(u >> 16);
}

// ---------------- weight transforms ----------------
// Wb[i][o'][kappa] bf16.  o'<256 -> filter o, o'>=256 -> gate o-256.
// kappa<256 -> current tap (w[...,1]), kappa>=256 -> previous tap (w[...,0]).
__global__ __launch_bounds__(256) void transform_fgb(
    const float* __restrict__ wf, const float* __restrict__ wg, unsigned short* __restrict__ Wb)
{
  int idx = blockIdx.x * 256 + threadIdx.x;    // < 32*512*512
  int kap = idx & 511;
  int op  = (idx >> 9) & 511;
  int i   = idx >> 18;
  int o = op & 255, c = kap & 255;
  int k = (kap < 256) ? 1 : 0;
  const float* src = (op < 256) ? wf : wg;
  Wb[idx] = f2bf(src[(((i * 256 + o) * 256 + c) << 1) + k]);
}

// Wrb[i][o][c] bf16 (w_res already [o][c])
__global__ __launch_bounds__(256) void transform_resb(
    const float* __restrict__ wr, unsigned short* __restrict__ Wrb)
{
  int idx = blockIdx.x * 256 + threadIdx.x;    // < 32*256*256/4
  float4 v = ((const float4*)wr)[idx];
  uint2 o;
  o.x = (unsigned)f2bf(v.x) | ((unsigned)f2bf(v.y) << 16);
  o.y = (unsigned)f2bf(v.z) | ((unsigned)f2bf(v.w) << 16);
  ((uint2*)Wrb)[idx] = o;
}

// wskT[i][c][s] = w_skip[i][s][c]  (fp32, for head)
__global__ __launch_bounds__(256) void transform_skip(
    const float* __restrict__ wsk, float* __restrict__ wskT)
{
  int idx = blockIdx.x * 256 + threadIdx.x;    // < 32*256*128
  int s = idx & 127;
  int c = (idx >> 7) & 255;
  int i = idx >> 15;
  wskT[idx] = wsk[(i * 128 + s) * 256 + c];
}

// ---------------- input conv (F=32 -> R=256, K=2, d=1) ----------------
__global__ __launch_bounds__(256) void in_conv(
    const float* __restrict__ X, const float* __restrict__ w_in,
    const float* __restrict__ b_in, float* __restrict__ xb,
    unsigned short* __restrict__ xbb)
{
  int g = blockIdx.x;       // 0..127 (8 time steps each)
  int b = blockIdx.y;
  int r = threadIdx.x;      // 0..255
  __shared__ float Xs[9][32];
  int tt0 = 3 + g * 8;
  int t0  = tt0 + 1024;
  for (int idx = r; idx < 288; idx += 256) {
    int row = idx >> 5, f = idx & 31;
    int t = t0 - 1 + row;
    if (t > 2047) t = 2047;
    Xs[row][f] = X[(b * 2048 + t) * 32 + f];
  }
  if (g == 0) {
    #pragma unroll
    for (int t2 = 0; t2 < 3; t2++) {
      size_t off = ((size_t)b * TBUF + t2) * RCH + r;
      xb[off] = 0.f; xbb[off] = 0;
    }
  }
  __syncthreads();
  float acc[8] = {0,0,0,0,0,0,0,0};
  const float* w = w_in + r * 64;
  #pragma unroll
  for (int f = 0; f < 32; f++) {
    float w0 = w[f * 2 + 0];
    float w1 = w[f * 2 + 1];
    #pragma unroll
    for (int j = 0; j < 8; j++)
      acc[j] = fmaf(w1, Xs[j + 1][f], fmaf(w0, Xs[j][f], acc[j]));
  }
  float bias = b_in[r];
  #pragma unroll
  for (int j = 0; j < 8; j++) {
    int tt = tt0 + j;
    if (tt <= 1023) {
      float v = acc[j] + bias;
      size_t off = ((size_t)b * TBUF + tt) * RCH + r;
      xb[off] = v; xbb[off] = f2bf(v);
    }
  }
}

// ---------------- fused layer: gated dilated conv + res 1x1 + residual ----------------
// 512 threads = 8 waves. Block tile: M=64 time rows, full N (512 conv / 256 res).
// Wave w owns output cols [32w,32w+32) of f AND g (conv), of o (res).
// A-tile (64 x 512, both taps) staged ONCE in LDS, XOR-swizzled; no barriers in K-loop.
// B streams L2->regs. z (64x256) aliases the A-tile LDS after conv completes.
// bf16 x-mirror is ping-ponged across layers (intra-dispatch RAW avoidance);
// fp32 x master updated in place (blocks touch only their own rows).
__global__ __launch_bounds__(512, 4) void layer_fused(
    const unsigned short* __restrict__ xbb_r, float* __restrict__ xb,
    unsigned short* __restrict__ xbb_w,
    const unsigned short* __restrict__ Wb,   // [512][512] bf16
    const unsigned short* __restrict__ Wrb,  // [256][256] bf16
    const float* __restrict__ bF, const float* __restrict__ bG,
    const float* __restrict__ bR,
    int dd, int t_lo, float* __restrict__ fxs_i)
{
  __shared__ __align__(16) unsigned short As[64 * 520];   // 66,560 B; z aliases
  const int tid  = threadIdx.x;
  const int w    = tid >> 6;
  const int lane = tid & 63;
  const int l15  = lane & 15;
  const int lk8  = (lane >> 4) << 3;          // k-elem offset {0,8,16,24}
  const int sw   = (l15 & 7) << 4;            // XOR swizzle (row&7 == l15&7 for our rows)
  const int tt0  = t_lo + (int)blockIdx.x * 64;
  const int b    = blockIdx.y;
  const unsigned short* xB = xbb_r + ((size_t)b << 18);

  // ---- stage full A tile: 64 rows x 512 k  (k<256: x[tt], k>=256: x[tt-d])
  #pragma unroll
  for (int it = 0; it < 8; ++it) {
    int flat = it * 512 + tid;
    int r = flat >> 6;                 // 0..63
    int c = flat & 63;                 // 16B slot within row
    int tap = c >> 5;
    int tt = tt0 + r - tap * dd;
    tt = min(max(tt, 0), 1023);
    uint4 v = *(const uint4*)&xB[((size_t)tt << 8) + ((c & 31) << 3)];
    *(uint4*)((char*)As + r * 1040 + ((c << 4) ^ ((r & 7) << 4))) = v;
  }
  __syncthreads();

  // ---- conv GEMM (no barriers): per wave 64(M) x {32 f + 32 g}
  f32x4 accf[4][2] = {};
  f32x4 accg[4][2] = {};
  const unsigned short* wf0 = Wb + (size_t)(32 * w + l15) * 512 + lk8;
  const unsigned short* wf1 = wf0 + (size_t)16 * 512;
  const unsigned short* wg0 = wf0 + (size_t)256 * 512;
  const unsigned short* wg1 = wf0 + (size_t)272 * 512;
  #pragma unroll 4
  for (int kc = 0; kc < 16; ++kc) {
    const int k0 = kc * 32;
    uint4 ubf0 = *(const uint4*)(wf0 + k0);
    uint4 ubf1 = *(const uint4*)(wf1 + k0);
    uint4 ubg0 = *(const uint4*)(wg0 + k0);
    uint4 ubg1 = *(const uint4*)(wg1 + k0);
    const int colb = (k0 + lk8) * 2;
    bf16x8 a[4];
    #pragma unroll
    for (int mf = 0; mf < 4; ++mf)
      a[mf] = *(const bf16x8*)((const char*)As + (mf * 16 + l15) * 1040 + (colb ^ sw));
    bf16x8 vf0 = __builtin_bit_cast(bf16x8, ubf0);
    bf16x8 vf1 = __builtin_bit_cast(bf16x8, ubf1);
    bf16x8 vg0 = __builtin_bit_cast(bf16x8, ubg0);
    bf16x8 vg1 = __builtin_bit_cast(bf16x8, ubg1);
    #pragma unroll
    for (int mf = 0; mf < 4; ++mf) {
      accf[mf][0] = __builtin_amdgcn_mfma_f32_16x16x32_bf16(a[mf], vf0, accf[mf][0], 0, 0, 0);
      accf[mf][1] = __builtin_amdgcn_mfma_f32_16x16x32_bf16(a[mf], vf1, accf[mf][1], 0, 0, 0);
      accg[mf][0] = __builtin_amdgcn_mfma_f32_16x16x32_bf16(a[mf], vg0, accg[mf][0], 0, 0, 0);
      accg[mf][1] = __builtin_amdgcn_mfma_f32_16x16x32_bf16(a[mf], vg1, accg[mf][1], 0, 0, 0);
    }
  }
  __syncthreads();   // all As reads done -> safe to overwrite with z

  // ---- gate epilogue: z = tanh(f+bf) * sigmoid(g+bg) -> LDS (aliased, swizzled)
  unsigned short* Zs = As;
  const int rr0 = (lane >> 4) << 2;            // 0,4,8,12
  const float bfv[2] = { bF[32 * w + l15], bF[32 * w + 16 + l15] };
  const float bgv[2] = { bG[32 * w + l15], bG[32 * w + 16 + l15] };
  #pragma unroll
  for (int mf = 0; mf < 4; ++mf)
    #pragma unroll
    for (int nf = 0; nf < 2; ++nf) {
      int col = 32 * w + nf * 16 + l15;
      #pragma unroll
      for (int j = 0; j < 4; ++j) {
        int row = mf * 16 + rr0 + j;
        float pf = accf[mf][nf][j] + bfv[nf];
        float pg = accg[mf][nf][j] + bgv[nf];
        float e2 = __expf(2.f * pf);
        float th = 1.f - 2.f / (e2 + 1.f);
        float sg = 1.f / (1.f + __expf(-pg));
        *(unsigned short*)((char*)Zs + row * 528 + ((col * 2) ^ ((row & 7) << 4))) = f2bf(th * sg);
      }
    }
  __syncthreads();

  // ---- res GEMM: per wave 64(M) x 32(N), K=256 from z-LDS
  f32x4 acc[4][2] = {};
  const unsigned short* wr0 = Wrb + (size_t)(32 * w + l15) * 256 + lk8;
  const unsigned short* wr1 = wr0 + (size_t)16 * 256;
  #pragma unroll 4
  for (int kc = 0; kc < 8; ++kc) {
    const int k0 = kc * 32;
    uint4 ur0 = *(const uint4*)(wr0 + k0);
    uint4 ur1 = *(const uint4*)(wr1 + k0);
    const int colb = (k0 + lk8) * 2;
    bf16x8 a[4];
    #pragma unroll
    for (int mf = 0; mf < 4; ++mf)
      a[mf] = *(const bf16x8*)((const char*)Zs + (mf * 16 + l15) * 528 + (colb ^ sw));
    bf16x8 v0 = __builtin_bit_cast(bf16x8, ur0);
    bf16x8 v1 = __builtin_bit_cast(bf16x8, ur1);
    #pragma unroll
    for (int mf = 0; mf < 4; ++mf) {
      acc[mf][0] = __builtin_amdgcn_mfma_f32_16x16x32_bf16(a[mf], v0, acc[mf][0], 0, 0, 0);
      acc[mf][1] = __builtin_amdgcn_mfma_f32_16x16x32_bf16(a[mf], v1, acc[mf][1], 0, 0, 0);
    }
  }

  // ---- residual epilogue: fx = acc + bR; x += fx (fp32 master, in place);
  //      bf16 mirror -> xbb_w (next layer's input buffer); snapshot fx at tt==1023
  const float brv[2] = { bR[32 * w + l15], bR[32 * w + 16 + l15] };
  float* xBf = xb + ((size_t)b << 18);
  unsigned short* xBb = xbb_w + ((size_t)b << 18);
  #pragma unroll
  for (int mf = 0; mf < 4; ++mf)
    #pragma unroll
    for (int j = 0; j < 4; ++j) {
      int tt = tt0 + mf * 16 + rr0 + j;
      if (tt > 1023) continue;
      #pragma unroll
      for (int nf = 0; nf < 2; ++nf) {
        int o = 32 * w + nf * 16 + l15;
        size_t off = ((size_t)tt << 8) + o;
        float fx = acc[mf][nf][j] + brv[nf];
        float xn = xBf[off] + fx;
        xBf[off] = xn;
        xBb[off] = f2bf(xn);
        if (tt == 1023) fxs_i[(size_t)b * 256 + o] = fx;
      }
    }
}

// ---------------- head ----------------
__global__ __launch_bounds__(128) void skip_partial(
    const float* __restrict__ fxs, const float* __restrict__ wskT,
    const float* __restrict__ b_skip, float* __restrict__ part)
{
  int i = blockIdx.x, b = blockIdx.y, s = threadIdx.x;
  __shared__ float fxsh[256];
  fxsh[s]       = fxs[((size_t)i * 16 + b) * 256 + s];
  fxsh[s + 128] = fxs[((size_t)i * 16 + b) * 256 + s + 128];
  __syncthreads();
  float a = b_skip[i * 128 + s];
  const float* wp = wskT + (size_t)i * 256 * 128 + s;
  #pragma unroll 4
  for (int c = 0; c < 256; c++)
    a = fmaf(wp[c * 128], fxsh[c], a);
  part[((size_t)i * 16 + b) * 128 + s] = a;
}

__global__ __launch_bounds__(128) void head2(
    const float* __restrict__ part, const float* __restrict__ w_o1,
    const float* __restrict__ b_o1, const float* __restrict__ w_o2,
    const float* __restrict__ b_o2, const float* __restrict__ w_lin,
    const float* __restrict__ b_lin, const float* __restrict__ Xex,
    float* __restrict__ out)
{
  int b = blockIdx.x, tid = threadIdx.x;
  __shared__ float sk[128];
  __shared__ float h1[64];
  __shared__ float hc[80];
  float a = 0.f;
  for (int i = 0; i < 32; i++) a += part[((size_t)i * 16 + b) * 128 + tid];
  sk[tid] = fmaxf(a, 0.f);
  __syncthreads();
  if (tid < 64) {
    float a1 = b_o1[tid];
    for (int s = 0; s < 128; s++) a1 = fmaf(w_o1[tid * 128 + s], sk[s], a1);
    h1[tid] = fmaxf(a1, 0.f);
  }
  __syncthreads();
  if (tid < 64) {
    float a2 = b_o2[tid];
    for (int j = 0; j < 64; j++) a2 = fmaf(w_o2[tid * 64 + j], h1[j], a2);
    hc[tid] = fmaxf(a2, 0.f);
  }
  if (tid >= 64 && tid < 80) hc[tid] = fmaxf(Xex[b * 16 + (tid - 64)], 0.f);
  __syncthreads();
  if (tid < 24) {
    float a3 = b_lin[tid];
    for (int j = 0; j < 80; j++) a3 = fmaf(w_lin[tid * 80 + j], hc[j], a3);
    out[b * 24 + tid] = a3;
  }
}

extern "C" void kernel_launch(void* const* d_in, const int* in_sizes, int n_in,
                              void* d_out, int out_size, void* d_ws, size_t ws_size,
                              hipStream_t stream)
{
  (void)in_sizes; (void)n_in; (void)out_size; (void)ws_size;
  const float* X     = (const float*)d_in[0];
  const float* Xex   = (const float*)d_in[1];
  const float* w_in  = (const float*)d_in[2];
  const float* b_in  = (const float*)d_in[3];
  const float* w_f   = (const float*)d_in[4];
  const float* b_f   = (const float*)d_in[5];
  const float* w_g   = (const float*)d_in[6];
  const float* b_g   = (const float*)d_in[7];
  const float* w_r   = (const float*)d_in[8];
  const float* b_r   = (const float*)d_in[9];
  const float* w_s   = (const float*)d_in[10];
  const float* b_s   = (const float*)d_in[11];
  const float* w_o1  = (const float*)d_in[12];
  const float* b_o1  = (const float*)d_in[13];
  const float* w_o2  = (const float*)d_in[14];
  const float* b_o2  = (const float*)d_in[15];
  const float* w_lin = (const float*)d_in[16];
  const float* b_lin = (const float*)d_in[17];

  float* ws   = (float*)d_ws;
  float* wskT = ws;                        // 1,048,576 f
  float* xb   = wskT + 1048576;            // 4,194,304 f
  float* fxs  = xb   + 4194304;            // 131,072 f
  float* part = fxs  + 131072;             // 65,536 f
  unsigned short* Wb   = (unsigned short*)(part + 65536);  // 8,388,608 us
  unsigned short* Wrb  = Wb   + 8388608;   // 2,097,152 us
  unsigned short* xbbA = Wrb  + 2097152;   // 4,194,304 us
  unsigned short* xbbB = xbbA + 4194304;   // 4,194,304 us

  transform_fgb <<<32768, 256, 0, stream>>>(w_f, w_g, Wb);
  transform_resb<<<2048,  256, 0, stream>>>(w_r, Wrb);
  transform_skip<<<4096,  256, 0, stream>>>(w_s, wskT);
  in_conv<<<dim3(128, 16), 256, 0, stream>>>(X, w_in, b_in, xb, xbbA);

  // suffix-window sizes: w[i] = w[i+1] + 2^(i%8), w[32] = 1
  static const int wI[33] = {1021,1020,1018,1014,1006,990,958,894,
                             766,765,763,759,751,735,703,639,
                             511,510,508,504,496,480,448,384,
                             256,255,253,249,241,225,193,129,1};
  for (int i = 0; i < 32; i++) {
    int dd    = 1 << (i & 7);
    int Wout  = wI[i + 1];
    int t_lo  = TBUF - Wout;
    int tiles = (Wout + 63) / 64;
    unsigned short* xin  = (i & 1) ? xbbB : xbbA;
    unsigned short* xout = (i & 1) ? xbbA : xbbB;
    layer_fused<<<dim3(tiles, 16), 512, 0, stream>>>(
        xin, xb, xout,
        Wb + (size_t)i * 512 * 512, Wrb + (size_t)i * 256 * 256,
        b_f + i * 256, b_g + i * 256, b_r + i * 256,
        dd, t_lo, fxs + (size_t)i * 16 * 256);
  }
  skip_partial<<<dim3(32, 16), 128, 0, stream>>>(fxs, wskT, b_s, part);
  head2<<<16, 128, 0, stream>>>(part, w_o1, b_o1, w_o2, b_o2, w_lin, b_lin, Xex, (float*)d_out);
}